// Round 10
// baseline (3147.600 us; speedup 1.0000x reference)
//
#include <hip/hip_runtime.h>
#include <hip/hip_cooperative_groups.h>

namespace cg = cooperative_groups;

// LSTM S=512,B=128,IN=256,H=512 — persistent kernel, 256 blocks =
// 8 rowgroups(16 batch rows) x 32 colgroups(16 hidden cols).
// Round 10 = round 8's PROVEN always-LLC tagged bf16 ring (1 speculative RT,
// self-healing) + packed-gate waves: each wave computes ALL 4 gates for a
// 4-col slice (B packs 4 gates x 4 cols into the 16 MFMA cols), so the gate
// exchange is 3 in-wave shuffles (no gbuf LDS, no second barrier). Hs/Xs
// double-buffered -> ONE __syncthreads per step; waves publish h right after
// their own MFMA.

#define SQ   512
#define BB   128
#define IN_  256
#define HH   512
#define RG   8
#define CGN  32
#define RINGHALF (BB * HH)     // dwords
#define RING_OFF 1024          // dwords (4 KB head, unused)

typedef float    f32x4 __attribute__((ext_vector_type(4)));
typedef short    s16x8 __attribute__((ext_vector_type(8)));
typedef unsigned u32x4 __attribute__((ext_vector_type(4)));

struct P {
  const float *x, *h0, *c0;
  const float *W[4], *bW[4], *U[4], *bU[4];   // gate order f,i,o,g
  float* out;        // [SQ][BB][HH] h_seq, then [BB][HH] h, then [BB][HH] c
  unsigned* ring;    // [2][BB][HH] tagged bf16 h (lo16=payload, hi16=tag)
  int mode;          // 0 = ring protocol, 2 = gridsync fallback (no ws)
};

__device__ __forceinline__ unsigned f2b(float f) {
  unsigned u = __float_as_uint(f);
  return (u + 0x7FFFu + ((u >> 16) & 1u)) >> 16;   // RNE f32->bf16
}
__device__ __forceinline__ float sigm(float x) { return 1.f / (1.f + __expf(-x)); }
__device__ __forceinline__ float tanh_(float x) {
  float e = __expf(-2.f * fabsf(x));
  float t = (1.f - e) / (1.f + e);
  return copysignf(t, x);
}
__device__ __forceinline__ u32x4 pack8(f32x4 a, f32x4 b) {
  u32x4 d;
  d.x = f2b(a.x) | (f2b(a.y) << 16);
  d.y = f2b(a.z) | (f2b(a.w) << 16);
  d.z = f2b(b.x) | (f2b(b.y) << 16);
  d.w = f2b(b.z) | (f2b(b.w) << 16);
  return d;
}

// 8x dwordx4 from base+{0,256,...,1792}B, ONE waitcnt, LLC-coherent.
#define LOAD8_LLC(c0_,c1_,c2_,c3_,c4_,c5_,c6_,c7_,ptr_)                      \
  asm volatile(                                                              \
    "global_load_dwordx4 %0, %8, off sc0 sc1\n\t"                            \
    "global_load_dwordx4 %1, %8, off offset:256 sc0 sc1\n\t"                 \
    "global_load_dwordx4 %2, %8, off offset:512 sc0 sc1\n\t"                 \
    "global_load_dwordx4 %3, %8, off offset:768 sc0 sc1\n\t"                 \
    "global_load_dwordx4 %4, %8, off offset:1024 sc0 sc1\n\t"                \
    "global_load_dwordx4 %5, %8, off offset:1280 sc0 sc1\n\t"                \
    "global_load_dwordx4 %6, %8, off offset:1536 sc0 sc1\n\t"                \
    "global_load_dwordx4 %7, %8, off offset:1792 sc0 sc1\n\t"                \
    "s_waitcnt vmcnt(0)"                                                     \
    : "=&v"(c0_), "=&v"(c1_), "=&v"(c2_), "=&v"(c3_),                        \
      "=&v"(c4_), "=&v"(c5_), "=&v"(c6_), "=&v"(c7_)                         \
    : "v"(ptr_) : "memory")

__global__ void __launch_bounds__(256, 1) lstm_all(P p) {
  __shared__ unsigned short Hs[2][16][512];   // h bf16 dbuf, rows 1024B, XOR swz
  __shared__ unsigned short Xs[2][16][256];   // x bf16 dbuf, rows 512B, XOR swz

  const int tid = threadIdx.x;
  const int bid = blockIdx.x;
  const int r   = bid & 7;          // rowgroup
  const int cgi = bid >> 3;         // colgroup
  const int rb  = r * 16;
  const int hcb = cgi * 16;

  const int wv   = tid >> 6;        // wave: cols hcb + wv*4 + (0..3), all gates
  const int l    = tid & 63;
  const int l16  = l & 15;
  const int lk   = l >> 4;
  const int gate = l16 >> 2;        // 0=f,1=i,2=o,3=g
  const int csub = l16 & 3;
  const int row16 = tid >> 4;       // staging row 0..15
  const int n16   = tid & 15;

  unsigned* ring = p.ring;          // valid only in mode 0

  // ---- per-wave B fragments: 16 MFMA cols = 4 gates x 4 cols ----
  const int col = hcb + wv * 4 + csub;
  const float* Wg = p.W[gate];      // divergent gate -> one-time selects
  const float* Ug = p.U[gate];
  s16x8 bfrag[24];
#pragma unroll
  for (int kk = 0; kk < 24; ++kk) {
    int k = kk * 32 + lk * 8;
    const float* src = (kk < 8) ? (Wg + (size_t)col * IN_ + k)
                                : (Ug + (size_t)col * HH + (k - IN_));
    f32x4 a = *(const f32x4*)src;
    f32x4 b = *(const f32x4*)(src + 4);
    s16x8 v;
    v[0]=(short)f2b(a.x); v[1]=(short)f2b(a.y); v[2]=(short)f2b(a.z); v[3]=(short)f2b(a.w);
    v[4]=(short)f2b(b.x); v[5]=(short)f2b(b.y); v[6]=(short)f2b(b.z); v[7]=(short)f2b(b.w);
    bfrag[kk] = v;
  }
  const float bias = p.bW[gate][col] + p.bU[gate][col];

  // cell state: one f32 per output row (4 rows per lane); identical across
  // the 4 gate-lanes of each (row,col) — deterministic redundancy
  f32x4 cv;
#pragma unroll
  for (int rr = 0; rr < 4; ++rr)
    cv[rr] = p.c0[(size_t)(rb + lk * 4 + rr) * HH + col];

  const int wswz = (row16 & 7) << 4;   // staging-row byte-XOR key
  const int rswz = (l16 & 7) << 4;     // mfma-read byte-XOR key
  char* HsB = (char*)&Hs[0][0][0];
  char* XsB = (char*)&Xs[0][0][0];
  const bool b2 = (gate & 1) != 0;
  const bool b3 = (gate & 2) != 0;

  // ---- prologue: x(t=0) into registers ----
  f32x4 xg0, xg1, xg2, xg3;
  {
    const float* xs = p.x + (size_t)(rb + row16) * IN_ + n16 * 16;
    xg0 = *(const f32x4*)(xs);
    xg1 = *(const f32x4*)(xs + 4);
    xg2 = *(const f32x4*)(xs + 8);
    xg3 = *(const f32x4*)(xs + 12);
  }

  for (int t = 0; t < SQ; ++t) {
    const int half = t & 1;

    // ---- B) obtain h_{t-1} into Hs[half] (bf16, swizzled) — tagged ring ----
    char* hrow = HsB + half * 16384 + row16 * 1024;
    if (t == 0) {
      const float* src = p.h0 + (size_t)(rb + row16) * HH + n16 * 4;
#pragma unroll
      for (int cc = 0; cc < 8; ++cc) {
        f32x4 v = *(const f32x4*)(src + cc * 64);
        unsigned lo = f2b(v.x) | (f2b(v.y) << 16);
        unsigned hi = f2b(v.z) | (f2b(v.w) << 16);
        int boff = ((cc * 128 + n16 * 8) ^ wswz);
        *(uint2*)(hrow + boff) = make_uint2(lo, hi);
      }
    } else if (p.mode == 0) {
      const unsigned* hb = ring + (((t - 1) & 1) ? RINGHALF : 0)
                         + (size_t)(rb + row16) * HH + n16 * 4;
      u32x4 c0,c1,c2,c3,c4,c5,c6,c7;
      const unsigned tg = (unsigned)t;
#define TAGOK(v) (((v).x >> 16) == tg && ((v).y >> 16) == tg && \
                  ((v).z >> 16) == tg && ((v).w >> 16) == tg)
      int spin = 0;
      for (;;) {
        LOAD8_LLC(c0,c1,c2,c3,c4,c5,c6,c7,hb);
        if (TAGOK(c0) && TAGOK(c1) && TAGOK(c2) && TAGOK(c3) &&
            TAGOK(c4) && TAGOK(c5) && TAGOK(c6) && TAGOK(c7)) break;
        if (++spin > (1 << 16)) break;   // bounded: fail loud, never hang
        if (spin > 8) __builtin_amdgcn_s_sleep(1);
      }
#undef TAGOK
      u32x4 cvv[8] = {c0,c1,c2,c3,c4,c5,c6,c7};
#pragma unroll
      for (int cc = 0; cc < 8; ++cc) {
        unsigned lo = (cvv[cc].x & 0xFFFFu) | (cvv[cc].y << 16);
        unsigned hi = (cvv[cc].z & 0xFFFFu) | (cvv[cc].w << 16);
        int boff = ((cc * 128 + n16 * 8) ^ wswz);
        *(uint2*)(hrow + boff) = make_uint2(lo, hi);
      }
    } else {
      cg::this_grid().sync();
      const float* hp = p.out + ((size_t)(t - 1) * BB + rb + row16) * HH + n16 * 4;
      u32x4 a0,a1,a2,a3,a4,a5,a6,a7;
      LOAD8_LLC(a0,a1,a2,a3,a4,a5,a6,a7,hp);
      u32x4 av[8] = {a0,a1,a2,a3,a4,a5,a6,a7};
#pragma unroll
      for (int cc = 0; cc < 8; ++cc) {
        unsigned lo = f2b(__uint_as_float(av[cc].x)) | (f2b(__uint_as_float(av[cc].y)) << 16);
        unsigned hi = f2b(__uint_as_float(av[cc].z)) | (f2b(__uint_as_float(av[cc].w)) << 16);
        int boff = ((cc * 128 + n16 * 8) ^ wswz);
        *(uint2*)(hrow + boff) = make_uint2(lo, hi);
      }
    }

    // ---- A) Xs[half] <- xreg; issue x(t+1) loads (off critical path) ----
    {
      char* xrow = XsB + half * 8192 + row16 * 512;
      *(u32x4*)(xrow + ((n16 * 32)      ^ wswz)) = pack8(xg0, xg1);
      *(u32x4*)(xrow + ((n16 * 32 + 16) ^ wswz)) = pack8(xg2, xg3);
      if (t + 1 < SQ) {
        const float* xs = p.x + ((size_t)(t + 1) * BB + rb + row16) * IN_ + n16 * 16;
        xg0 = *(const f32x4*)(xs);
        xg1 = *(const f32x4*)(xs + 4);
        xg2 = *(const f32x4*)(xs + 8);
        xg3 = *(const f32x4*)(xs + 12);
      }
    }
    __syncthreads();   // the ONLY barrier per step

    // ---- D) 24 MFMAs: 8 from Xs, 16 from Hs ----
    f32x4 acc0 = { bias, bias, bias, bias };
    f32x4 acc1 = { 0.f, 0.f, 0.f, 0.f };
    const char* xr = XsB + half * 8192  + l16 * 512;
    const char* hr = HsB + half * 16384 + l16 * 1024;
#pragma unroll
    for (int kp = 0; kp < 8; kp += 2) {
      s16x8 a0 = *(const s16x8*)(xr + ((kp * 64 + lk * 16)       ^ rswz));
      s16x8 a1 = *(const s16x8*)(xr + (((kp + 1) * 64 + lk * 16) ^ rswz));
      acc0 = __builtin_amdgcn_mfma_f32_16x16x32_bf16(a0, bfrag[kp],     acc0, 0, 0, 0);
      acc1 = __builtin_amdgcn_mfma_f32_16x16x32_bf16(a1, bfrag[kp + 1], acc1, 0, 0, 0);
    }
#pragma unroll
    for (int kp = 0; kp < 16; kp += 2) {
      s16x8 a0 = *(const s16x8*)(hr + ((kp * 64 + lk * 16)       ^ rswz));
      s16x8 a1 = *(const s16x8*)(hr + (((kp + 1) * 64 + lk * 16) ^ rswz));
      acc0 = __builtin_amdgcn_mfma_f32_16x16x32_bf16(a0, bfrag[8 + kp], acc0, 0, 0, 0);
      acc1 = __builtin_amdgcn_mfma_f32_16x16x32_bf16(a1, bfrag[9 + kp], acc1, 0, 0, 0);
    }

    // ---- E/F) activation + in-wave gate exchange + cell update ----
    // D-frag: lane holds (row=lk*4+rr, gate=l16>>2, csub=l16&3)
    float hv[4];
#pragma unroll
    for (int rr = 0; rr < 4; ++rr) {
      float v  = acc0[rr] + acc1[rr];
      float sg = sigm(v);
      float th = tanh_(v);
      float va = (b2 && b3) ? th : sg;           // gate 3 -> tanh, else sigm
      float x1 = __shfl_xor(va, 4);              // gate ^ 1
      float x2 = __shfl_xor(va, 8);              // gate ^ 2
      float x3 = __shfl_xor(va, 12);             // gate ^ 3
      float fg = b3 ? (b2 ? x3 : x2) : (b2 ? x1 : va);
      float ig = b3 ? (b2 ? x2 : x3) : (b2 ? va : x1);
      float og = b3 ? (b2 ? x1 : va) : (b2 ? x3 : x2);
      float gg = b3 ? (b2 ? va : x1) : (b2 ? x2 : x3);
      cv[rr] = fg * cv[rr] + ig * gg;
      hv[rr] = og * tanh_(cv[rr]);
    }

    // ---- G) publish (gate-0 lanes cover the wave's 16 rows x 4 cols) ----
    if (p.mode == 0) {
      if (gate == 0) {
#pragma unroll
        for (int rr = 0; rr < 4; ++rr) {
          int row = rb + lk * 4 + rr;
          unsigned tw = ((unsigned)(t + 1) << 16) | f2b(hv[rr]);
          unsigned* dst = ring + (half ? RINGHALF : 0) + (size_t)row * HH + col;
          asm volatile("global_store_dword %0, %1, off sc0 sc1"
                       :: "v"(dst), "v"(tw) : "memory");
          __builtin_nontemporal_store(hv[rr],
              p.out + ((size_t)t * BB + row) * HH + col);
        }
      }
    } else {
      if (gate == 0) {
#pragma unroll
        for (int rr = 0; rr < 4; ++rr) {
          int row = rb + lk * 4 + rr;
          asm volatile("global_store_dword %0, %1, off sc0 sc1"
                       :: "v"(p.out + ((size_t)t * BB + row) * HH + col),
                          "v"(hv[rr]) : "memory");
        }
      }
      asm volatile("s_waitcnt vmcnt(0)" ::: "memory");
    }
    if (t == SQ - 1 && gate == 0) {
      size_t base = (size_t)SQ * BB * HH;
#pragma unroll
      for (int rr = 0; rr < 4; ++rr) {
        size_t idx2 = (size_t)(rb + lk * 4 + rr) * HH + col;
        p.out[base + idx2] = hv[rr];
        p.out[base + (size_t)BB * HH + idx2] = cv[rr];
      }
    }
    // reuse safety: Hs/Xs[half] rewritten at t+2 only after barrier(t+1),
    // which implies all waves completed MFMA(t). Ring WAR as in round 8.
  }
}

extern "C" void kernel_launch(void* const* d_in, const int* in_sizes, int n_in,
                              void* d_out, int out_size, void* d_ws, size_t ws_size,
                              hipStream_t stream) {
  P p;
  p.x  = (const float*)d_in[0];
  p.h0 = (const float*)d_in[1];
  p.c0 = (const float*)d_in[2];
  for (int g = 0; g < 4; ++g) {
    p.W[g]  = (const float*)d_in[3 + 4 * g];
    p.bW[g] = (const float*)d_in[4 + 4 * g];
    p.U[g]  = (const float*)d_in[5 + 4 * g];
    p.bU[g] = (const float*)d_in[6 + 4 * g];
  }
  p.out = (float*)d_out;

  const size_t need = (size_t)(RING_OFF + 2 * BB * HH) * sizeof(unsigned);
  const bool ws_ok = (d_ws != nullptr) && (ws_size >= need);
  p.mode = ws_ok ? 0 : 2;
  p.ring = ws_ok ? ((unsigned*)d_ws + RING_OFF) : nullptr;
  if (ws_ok) hipMemsetAsync(d_ws, 0, need, stream);   // tags=0: never valid

  void* args[] = { &p };
  hipError_t e = hipLaunchCooperativeKernel((const void*)lstm_all,
                                            dim3(RG * CGN), dim3(256),
                                            args, 0, stream);
  if (e != hipSuccess) {
    // plain launch: 256 blocks at 1/CU are co-resident; ring protocol valid
    hipLaunchKernelGGL(lstm_all, dim3(RG * CGN), dim3(256), 0, stream, p);
  }
}

// Round 11
// 1478.527 us; speedup vs baseline: 2.1289x; 2.1289x over previous
//
#include <hip/hip_runtime.h>
#include <hip/hip_cooperative_groups.h>

namespace cg = cooperative_groups;

// LSTM S=512,B=128,IN=256,H=512 — persistent kernel.
// Round 11 = round 8's PROVEN protocol (always-LLC tagged bf16 ring, 1
// speculative RT, self-healing; coalesced per-thread loads/stores; gbuf gate
// exchange; 2 barriers/step) with colgroup consolidation: 128 blocks x 512
// threads (16 rows x 32 cols x 4 gates each). Halves per-step LLC traffic
// (ring reads 8->4 MB, x staging 4->2 MB) by halving consumers per rowgroup.

#define SQ   512
#define BB   128
#define IN_  256
#define HH   512
#define RG   8
#define CGN  16                // colgroups (32 cols each)
#define RINGHALF (BB * HH)     // dwords
#define RING_OFF 1024          // dwords (4 KB head, unused)

typedef float    f32x4 __attribute__((ext_vector_type(4)));
typedef short    s16x8 __attribute__((ext_vector_type(8)));
typedef unsigned u32x4 __attribute__((ext_vector_type(4)));

struct P {
  const float *x, *h0, *c0;
  const float *W[4], *bW[4], *U[4], *bU[4];   // gate order f,i,o,g
  float* out;        // [SQ][BB][HH] h_seq, then [BB][HH] h, then [BB][HH] c
  unsigned* ring;    // [2][BB][HH] tagged bf16 h (lo16=payload, hi16=tag)
  int mode;          // 0 = ring protocol, 2 = gridsync fallback (no ws)
};

__device__ __forceinline__ unsigned f2b(float f) {
  unsigned u = __float_as_uint(f);
  return (u + 0x7FFFu + ((u >> 16) & 1u)) >> 16;   // RNE f32->bf16
}
__device__ __forceinline__ float sigm(float x) { return 1.f / (1.f + __expf(-x)); }
__device__ __forceinline__ float tanh_(float x) {
  float e = __expf(-2.f * fabsf(x));
  float t = (1.f - e) / (1.f + e);
  return copysignf(t, x);
}
__device__ __forceinline__ u32x4 pack8(f32x4 a, f32x4 b) {
  u32x4 d;
  d.x = f2b(a.x) | (f2b(a.y) << 16);
  d.y = f2b(a.z) | (f2b(a.w) << 16);
  d.z = f2b(b.x) | (f2b(b.y) << 16);
  d.w = f2b(b.z) | (f2b(b.w) << 16);
  return d;
}

// 4x dwordx4 contiguous 64B, ONE waitcnt, LLC-coherent.
#define LOAD4_LLC(c0_,c1_,c2_,c3_,ptr_)                                      \
  asm volatile(                                                              \
    "global_load_dwordx4 %0, %4, off sc0 sc1\n\t"                            \
    "global_load_dwordx4 %1, %4, off offset:16 sc0 sc1\n\t"                  \
    "global_load_dwordx4 %2, %4, off offset:32 sc0 sc1\n\t"                  \
    "global_load_dwordx4 %3, %4, off offset:48 sc0 sc1\n\t"                  \
    "s_waitcnt vmcnt(0)"                                                     \
    : "=&v"(c0_), "=&v"(c1_), "=&v"(c2_), "=&v"(c3_)                         \
    : "v"(ptr_) : "memory")

__global__ void __launch_bounds__(512, 1) lstm_all(P p) {
  __shared__ unsigned short Hs[16][512];      // h bf16, rows 1024B, XOR swz
  __shared__ unsigned short Xs[2][16][256];   // x bf16 dbuf, rows 512B, XOR swz
  __shared__ float gbuf[4][16][33];

  const int tid = threadIdx.x;
  const int bid = blockIdx.x;
  const int r   = bid & 7;          // rowgroup
  const int cgi = bid >> 3;         // colgroup 0..15
  const int rb  = r * 16;
  const int hcb = cgi * 32;

  const int w8   = tid >> 6;        // wave 0..7
  const int gate = w8 >> 1;         // 0=f,1=i,2=o,3=g
  const int ct   = w8 & 1;          // col-tile within gate
  const int l    = tid & 63;
  const int l16  = l & 15;
  const int lk   = l >> 4;
  const int srow = tid >> 5;        // staging/update row 0..15
  const int sn   = tid & 31;        // staging/update lane 0..31

  unsigned* ring = p.ring;          // valid only in mode 0

  // ---- per-wave B fragments (W|U) -> registers, bf16, once ----
  const int colb = hcb + ct * 16 + l16;
  const float* Wg = p.W[gate];
  const float* Ug = p.U[gate];
  s16x8 bfrag[24];
#pragma unroll
  for (int kk = 0; kk < 24; ++kk) {
    int k = kk * 32 + lk * 8;
    const float* src = (kk < 8) ? (Wg + (size_t)colb * IN_ + k)
                                : (Ug + (size_t)colb * HH + (k - IN_));
    f32x4 a = *(const f32x4*)src;
    f32x4 b = *(const f32x4*)(src + 4);
    s16x8 v;
    v[0]=(short)f2b(a.x); v[1]=(short)f2b(a.y); v[2]=(short)f2b(a.z); v[3]=(short)f2b(a.w);
    v[4]=(short)f2b(b.x); v[5]=(short)f2b(b.y); v[6]=(short)f2b(b.z); v[7]=(short)f2b(b.w);
    bfrag[kk] = v;
  }
  const float bias = p.bW[gate][colb] + p.bU[gate][colb];
  float cval = p.c0[(size_t)(rb + srow) * HH + hcb + sn];

  const int wswz = (srow & 7) << 4;    // staging-row byte-XOR key
  const int rswz = (l16 & 7) << 4;     // mfma-read byte-XOR key
  char* HsB = (char*)&Hs[0][0];
  char* XsB = (char*)&Xs[0][0][0];

  // ---- prologue: x(t=0) into registers (8 f32/thread) ----
  f32x4 xg0, xg1;
  {
    const float* xs = p.x + (size_t)(rb + srow) * IN_ + sn * 8;
    xg0 = *(const f32x4*)(xs);
    xg1 = *(const f32x4*)(xs + 4);
  }

  for (int t = 0; t < SQ; ++t) {
    // ---- A) Xs[t&1] <- xreg; issue x(t+1) loads (hide under the poll) ----
    {
      char* xrow = XsB + (t & 1) * 8192 + srow * 512;
      *(u32x4*)(xrow + ((sn * 16) ^ wswz)) = pack8(xg0, xg1);
      if (t + 1 < SQ) {
        const float* xs = p.x + ((size_t)(t + 1) * BB + rb + srow) * IN_ + sn * 8;
        xg0 = *(const f32x4*)(xs);
        xg1 = *(const f32x4*)(xs + 4);
      }
    }

    // ---- B) obtain h_{t-1} into Hs (bf16, swizzled) — tagged LLC ring ----
    char* hrow = HsB + srow * 1024;
    if (t == 0) {
      const float* hs = p.h0 + (size_t)(rb + srow) * HH + sn * 16;
      f32x4 a0 = *(const f32x4*)(hs);
      f32x4 b0 = *(const f32x4*)(hs + 4);
      f32x4 a1 = *(const f32x4*)(hs + 8);
      f32x4 b1 = *(const f32x4*)(hs + 12);
      *(u32x4*)(hrow + ((sn * 32)      ^ wswz)) = pack8(a0, b0);
      *(u32x4*)(hrow + ((sn * 32 + 16) ^ wswz)) = pack8(a1, b1);
    } else if (p.mode == 0) {
      const unsigned* hb = ring + (((t - 1) & 1) ? RINGHALF : 0)
                         + (size_t)(rb + srow) * HH + sn * 16;
      u32x4 c0, c1, c2, c3;
      const unsigned tg = (unsigned)t;
#define TAGOK(v) (((v).x >> 16) == tg && ((v).y >> 16) == tg && \
                  ((v).z >> 16) == tg && ((v).w >> 16) == tg)
      int spin = 0;
      for (;;) {
        LOAD4_LLC(c0, c1, c2, c3, hb);
        if (TAGOK(c0) && TAGOK(c1) && TAGOK(c2) && TAGOK(c3)) break;
        if (++spin > (1 << 16)) break;   // bounded: fail loud, never hang
        if (spin > 8) __builtin_amdgcn_s_sleep(1);
      }
#undef TAGOK
      u32x4 w0, w1;
      w0.x = (c0.x & 0xFFFFu) | (c0.y << 16);
      w0.y = (c0.z & 0xFFFFu) | (c0.w << 16);
      w0.z = (c1.x & 0xFFFFu) | (c1.y << 16);
      w0.w = (c1.z & 0xFFFFu) | (c1.w << 16);
      w1.x = (c2.x & 0xFFFFu) | (c2.y << 16);
      w1.y = (c2.z & 0xFFFFu) | (c2.w << 16);
      w1.z = (c3.x & 0xFFFFu) | (c3.y << 16);
      w1.w = (c3.z & 0xFFFFu) | (c3.w << 16);
      *(u32x4*)(hrow + ((sn * 32)      ^ wswz)) = w0;
      *(u32x4*)(hrow + ((sn * 32 + 16) ^ wswz)) = w1;
    } else {
      // gridsync fallback: f32 h from d_out via LLC
      cg::this_grid().sync();
      const float* hp = p.out + ((size_t)(t - 1) * BB + rb + srow) * HH + sn * 16;
      u32x4 a0, a1, a2, a3;
      LOAD4_LLC(a0, a1, a2, a3, hp);
      f32x4 f0 = __builtin_bit_cast(f32x4, a0);
      f32x4 f1 = __builtin_bit_cast(f32x4, a1);
      f32x4 f2 = __builtin_bit_cast(f32x4, a2);
      f32x4 f3 = __builtin_bit_cast(f32x4, a3);
      *(u32x4*)(hrow + ((sn * 32)      ^ wswz)) = pack8(f0, f1);
      *(u32x4*)(hrow + ((sn * 32 + 16) ^ wswz)) = pack8(f2, f3);
    }
    __syncthreads();   // Xs[t&1] + Hs ready

    // ---- D) 24 MFMAs: 8 from Xs (K=0..255), 16 from Hs (K=256..767) ----
    f32x4 acc0 = { bias, bias, bias, bias };
    f32x4 acc1 = { 0.f, 0.f, 0.f, 0.f };
    const char* xr = XsB + (t & 1) * 8192 + l16 * 512;
    const char* hr = HsB + l16 * 1024;
#pragma unroll
    for (int kp = 0; kp < 8; kp += 2) {
      s16x8 a0 = *(const s16x8*)(xr + ((kp * 64 + lk * 16)       ^ rswz));
      s16x8 a1 = *(const s16x8*)(xr + (((kp + 1) * 64 + lk * 16) ^ rswz));
      acc0 = __builtin_amdgcn_mfma_f32_16x16x32_bf16(a0, bfrag[kp],     acc0, 0, 0, 0);
      acc1 = __builtin_amdgcn_mfma_f32_16x16x32_bf16(a1, bfrag[kp + 1], acc1, 0, 0, 0);
    }
#pragma unroll
    for (int kp = 0; kp < 16; kp += 2) {
      s16x8 a0 = *(const s16x8*)(hr + ((kp * 64 + lk * 16)       ^ rswz));
      s16x8 a1 = *(const s16x8*)(hr + (((kp + 1) * 64 + lk * 16) ^ rswz));
      acc0 = __builtin_amdgcn_mfma_f32_16x16x32_bf16(a0, bfrag[8 + kp], acc0, 0, 0, 0);
      acc1 = __builtin_amdgcn_mfma_f32_16x16x32_bf16(a1, bfrag[9 + kp], acc1, 0, 0, 0);
    }

    // ---- E) activations -> gbuf (D-frag: row=lk*4+rr, col=l16) ----
#pragma unroll
    for (int rr = 0; rr < 4; ++rr) {
      float v = acc0[rr] + acc1[rr];
      v = (gate < 3) ? sigm(v) : tanh_(v);
      gbuf[gate][lk * 4 + rr][ct * 16 + l16] = v;
    }
    __syncthreads();

    // ---- F) cell update + publish (coalesced: 32 lanes = 128B lines) ----
    float f = gbuf[0][srow][sn];
    float i = gbuf[1][srow][sn];
    float o = gbuf[2][srow][sn];
    float g = gbuf[3][srow][sn];
    cval = f * cval + i * g;
    float h = o * tanh_(cval);

    size_t oidx = ((size_t)t * BB + rb + srow) * HH + hcb + sn;
    if (p.mode == 0) {
      unsigned tw = ((unsigned)(t + 1) << 16) | f2b(h);
      unsigned* dst = ring + ((t & 1) ? RINGHALF : 0)
                    + (size_t)(rb + srow) * HH + hcb + sn;
      asm volatile("global_store_dword %0, %1, off sc0 sc1"
                   :: "v"(dst), "v"(tw) : "memory");
      __builtin_nontemporal_store(h, p.out + oidx);
    } else {
      asm volatile("global_store_dword %0, %1, off sc0 sc1"
                   :: "v"(p.out + oidx), "v"(h) : "memory");
      asm volatile("s_waitcnt vmcnt(0)" ::: "memory");
    }
    if (t == SQ - 1) {
      size_t base = (size_t)SQ * BB * HH;
      size_t idx2 = (size_t)(rb + srow) * HH + hcb + sn;
      p.out[base + idx2] = h;
      p.out[base + (size_t)BB * HH + idx2] = cval;
    }
    // reuse safety: Hs/gbuf rewritten at t+1 only after this step's barriers
  }
}

extern "C" void kernel_launch(void* const* d_in, const int* in_sizes, int n_in,
                              void* d_out, int out_size, void* d_ws, size_t ws_size,
                              hipStream_t stream) {
  P p;
  p.x  = (const float*)d_in[0];
  p.h0 = (const float*)d_in[1];
  p.c0 = (const float*)d_in[2];
  for (int g = 0; g < 4; ++g) {
    p.W[g]  = (const float*)d_in[3 + 4 * g];
    p.bW[g] = (const float*)d_in[4 + 4 * g];
    p.U[g]  = (const float*)d_in[5 + 4 * g];
    p.bU[g] = (const float*)d_in[6 + 4 * g];
  }
  p.out = (float*)d_out;

  const size_t need = (size_t)(RING_OFF + 2 * BB * HH) * sizeof(unsigned);
  const bool ws_ok = (d_ws != nullptr) && (ws_size >= need);
  p.mode = ws_ok ? 0 : 2;
  p.ring = ws_ok ? ((unsigned*)d_ws + RING_OFF) : nullptr;
  if (ws_ok) hipMemsetAsync(d_ws, 0, need, stream);   // tags=0: never valid

  void* args[] = { &p };
  hipError_t e = hipLaunchCooperativeKernel((const void*)lstm_all,
                                            dim3(RG * CGN), dim3(512),
                                            args, 0, stream);
  if (e != hipSuccess) {
    // plain launch: 128 blocks at 1/CU are co-resident; ring protocol valid
    hipLaunchKernelGGL(lstm_all, dim3(RG * CGN), dim3(512), 0, stream, p);
  }
}